// Round 11
// baseline (88.600 us; speedup 1.0000x reference)
//
#include <hip/hip_runtime.h>
#include <math.h>

typedef _Float16 h16;
typedef _Float16 h8 __attribute__((ext_vector_type(8)));
typedef float f32x4 __attribute__((ext_vector_type(4)));

__device__ inline void gl2lds16(const void* g, void* l) {
  __builtin_amdgcn_global_load_lds(
      (const __attribute__((address_space(1))) void*)g,
      (__attribute__((address_space(3))) void*)l, 16, 0, 0);
}

__device__ inline void barrier_raw() {
  asm volatile("" ::: "memory");
  __builtin_amdgcn_s_barrier();
  asm volatile("" ::: "memory");
}

#define VMCNT(N) asm volatile("s_waitcnt vmcnt(" #N ")" ::: "memory")
#define LGKM(N) asm volatile("s_waitcnt lgkmcnt(" #N ")" ::: "memory")

// ---------------- fused fp32 -> fp16 conversion (hs + 4 weights) ----------------
__global__ __launch_bounds__(256) void f2h_all(
    const float* __restrict__ hs, const float* __restrict__ w0,
    const float* __restrict__ w1, const float* __restrict__ w2,
    const float* __restrict__ w3, h16* __restrict__ dst, int hsN) {
  int i = (blockIdx.x * 256 + threadIdx.x) * 8;
  const int tot = hsN + 4 * 1048576;
  if (i >= tot) return;
  const float* src;
  int off;
  if (i < hsN) {
    src = hs; off = i;
  } else {
    int k = i - hsN;
    int seg = k >> 20;
    off = k & 1048575;
    src = seg == 0 ? w0 : seg == 1 ? w1 : seg == 2 ? w2 : w3;
  }
  float4 a = *(const float4*)(src + off);
  float4 b = *(const float4*)(src + off + 4);
  h8 o;
  o[0] = (h16)a.x; o[1] = (h16)a.y; o[2] = (h16)a.z; o[3] = (h16)a.w;
  o[4] = (h16)b.x; o[5] = (h16)b.y; o[6] = (h16)b.z; o[7] = (h16)b.w;
  *(h8*)(dst + i) = o;
}

// ---------------- QKV GEMM: 128x64 tiles, 6 blocks/CU (TLP-first) -------------
// m97-style single-buffer body (proven r7). 1536 blocks -> 6/CU, 24 waves/CU
// (vs r7's 12). LDS 17 KB: Ash 8K + Bsh 4K + per-wave epilogue slabs 5K.
// Waves 2x2: wave-tile 64 rows x 32 cols, acc[4][2]. Swizzle as r7 (0-conflict
// PMC-verified). Epilogue: per-wave 16x32 slab bounce, no block barriers.
__global__ __launch_bounds__(256, 6) void qkv10(
    const h16* __restrict__ A, const h16* __restrict__ Bw,
    const float* __restrict__ qb, const float* __restrict__ kb,
    const float* __restrict__ vb, h16* __restrict__ qo, h16* __restrict__ ko,
    h16* __restrict__ vo) {
  __shared__ __align__(16) h16 Ash[128 * 32];       // 8 KB
  __shared__ __align__(16) h16 Bsh[64 * 32];        // 4 KB
  __shared__ __align__(16) h16 Cw[4][16 * 40];      // 5 KB per-wave slabs

  const int tid = threadIdx.x;
  const int wid = tid >> 6, lane = tid & 63;
  const int lr = lane & 15, lg = lane >> 4;
  const int wr = wid >> 1, wc = wid & 1;            // 2x2 waves
  const int srow = tid >> 2;                        // staging row (0..63)
  const int csw = ((tid & 3) ^ ((srow >> 1) & 3)) * 8;  // inv-swizzled src col

  // L2-local XCD chunks of the 32x48 grid (8bm x 24bn per XCD)
  const int xcd = blockIdx.x & 7;
  const int i = blockIdx.x >> 3;          // 0..191
  const int bm = (xcd & 3) * 8 + (i & 7);     // 0..31
  const int bn = (xcd >> 2) * 24 + (i >> 3);  // 0..47
  const int row0 = bm * 128, col0s = bn * 64;

  const h16* Ag = A + (size_t)row0 * 1024;
  const h16* Bg = Bw + (size_t)bn * 64 * 1024;

  auto ldf = [&](const h16* base, int row) -> h8 {
    return *(const h8*)(base + row * 32 + (lg ^ ((row >> 1) & 3)) * 8);
  };

  f32x4 acc[4][2] = {};

  for (int t = 0; t < 32; ++t) {
    const int kof = t * 32 + csw;
    gl2lds16(Ag + (size_t)srow * 1024 + kof, &Ash[(wid * 16) * 32]);
    gl2lds16(Ag + (size_t)(64 + srow) * 1024 + kof, &Ash[(64 + wid * 16) * 32]);
    gl2lds16(Bg + (size_t)srow * 1024 + kof, &Bsh[(wid * 16) * 32]);
    __syncthreads();
    h8 af[4], bf[2];
#pragma unroll
    for (int m = 0; m < 4; ++m) af[m] = ldf(Ash, wr * 64 + m * 16 + lr);
#pragma unroll
    for (int n = 0; n < 2; ++n) bf[n] = ldf(Bsh, wc * 32 + n * 16 + lr);
    __builtin_amdgcn_s_setprio(1);
#pragma unroll
    for (int m = 0; m < 4; ++m)
#pragma unroll
      for (int n = 0; n < 2; ++n)
        acc[m][n] =
            __builtin_amdgcn_mfma_f32_16x16x32_f16(af[m], bf[n], acc[m][n], 0, 0, 0);
    __builtin_amdgcn_s_setprio(0);
    __syncthreads();
  }

  // epilogue: per-wave slab bounce (wave-private Cw[wid]; no block barriers)
  const int tsel = bn >> 4;               // 0:q 1:k 2:v
  const int colseg = (bn & 15) * 64;      // col segment within E
  const float* bp = tsel == 0 ? qb : (tsel == 1 ? kb : vb);
  h16* outp = tsel == 0 ? qo : (tsel == 1 ? ko : vo);

  const float bv0 = bp[colseg + wc * 32 + 0 * 16 + lr];
  const float bv1 = bp[colseg + wc * 32 + 1 * 16 + lr];

  const int erow = lane >> 2;             // 0..15 (4 lanes per row)
  const int eslot = lane & 3;             // h8 slot within 32 cols

#pragma unroll
  for (int m = 0; m < 4; ++m) {
    // write this wave's 16x32 sub-tile into its slab
#pragma unroll
    for (int j = 0; j < 4; ++j) {
      Cw[wid][(lg * 4 + j) * 40 + 0 * 16 + lr] = (h16)(acc[m][0][j] + bv0);
      Cw[wid][(lg * 4 + j) * 40 + 1 * 16 + lr] = (h16)(acc[m][1][j] + bv1);
    }
    LGKM(0);
    __builtin_amdgcn_sched_barrier(0);
    h8 v = *(const h8*)&Cw[wid][erow * 40 + eslot * 8];
    const int r = row0 + wr * 64 + m * 16 + erow;
    *(h8*)&outp[(size_t)r * 1024 + colseg + wc * 32 + eslot * 8] = v;
    LGKM(0);  // slab read complete before next m overwrites
    __builtin_amdgcn_sched_barrier(0);
  }
}

// ---------------- O-proj: 64x64 tiles, dbuf counted vmcnt, 4 blocks/CU --------
// 1024 blocks -> 4/CU (was 2/CU). 16 KB LDS dbuf; VMCNT(2) counted, 0 only at
// the final iter (r3 lesson). Waves 2x2, wave-tile 32x32, acc[2][2].
__global__ __launch_bounds__(256, 6) void oproj10(const h16* __restrict__ A,
                                                  const h16* __restrict__ Bw,
                                                  const float* __restrict__ b0,
                                                  float* __restrict__ Cf) {
  __shared__ __align__(16) h16 Abuf[2][64][32];
  __shared__ __align__(16) h16 Bbuf[2][64][32];

  const int tid = threadIdx.x;
  const int wid = tid >> 6, lane = tid & 63;
  const int lr = lane & 15, lg = lane >> 4;
  const int wr = wid >> 1, wc = wid & 1;
  const int srow = tid >> 2;
  const int csw = ((tid & 3) ^ ((srow >> 1) & 3)) * 8;

  const int xcd = blockIdx.x & 7;
  const int i = blockIdx.x >> 3;        // 0..127
  const int bm = xcd * 8 + (i & 7);     // 0..63
  const int bn = i >> 3;                // 0..15
  const int row0 = bm * 64, col0 = bn * 64;

  const h16* Ag = A + (size_t)row0 * 1024;
  const h16* Bg = Bw + (size_t)col0 * 1024;

  auto stage = [&](int t, int bi) {
    const int kof = t * 32 + csw;
    gl2lds16(Ag + (size_t)srow * 1024 + kof, &Abuf[bi][wid * 16][0]);
    gl2lds16(Bg + (size_t)srow * 1024 + kof, &Bbuf[bi][wid * 16][0]);
  };
  auto ldf = [&](const h16* base, int row) -> h8 {
    return *(const h8*)(base + row * 32 + (lg ^ ((row >> 1) & 3)) * 8);
  };

  f32x4 acc[2][2] = {};

  stage(0, 0);
  for (int t = 0; t < 32; ++t) {
    if (t < 31) {
      stage(t + 1, (t + 1) & 1);
      VMCNT(2);  // tile t's 2 calls landed; t+1's 2 in flight
    } else {
      VMCNT(0);  // nothing staged this iter (counted wait would be vacuous)
    }
    barrier_raw();
    const h16* Ar = &Abuf[t & 1][0][0];
    const h16* Br = &Bbuf[t & 1][0][0];
    h8 af[2], bf[2];
#pragma unroll
    for (int m = 0; m < 2; ++m) af[m] = ldf(Ar, wr * 32 + m * 16 + lr);
#pragma unroll
    for (int n = 0; n < 2; ++n) bf[n] = ldf(Br, wc * 32 + n * 16 + lr);
    __builtin_amdgcn_s_setprio(1);
#pragma unroll
    for (int m = 0; m < 2; ++m)
#pragma unroll
      for (int n = 0; n < 2; ++n)
        acc[m][n] =
            __builtin_amdgcn_mfma_f32_16x16x32_f16(af[m], bf[n], acc[m][n], 0, 0, 0);
    __builtin_amdgcn_s_setprio(0);
    barrier_raw();
  }

#pragma unroll
  for (int n = 0; n < 2; ++n) {
    const int cidx = col0 + wc * 32 + n * 16 + lr;
    const float bv = b0[cidx];
#pragma unroll
    for (int m = 0; m < 2; ++m)
#pragma unroll
      for (int j = 0; j < 4; ++j) {
        const int r = row0 + wr * 32 + m * 16 + lg * 4 + j;
        Cf[(size_t)r * 1024 + cidx] = acc[m][n][j] + bv;
      }
  }
}

// ---------------- sliding-window attention ([B,S,E] inputs, r7 exact) ---------
__global__ __launch_bounds__(256) void swattn(const h16* __restrict__ Q,
                                              const h16* __restrict__ K,
                                              const h16* __restrict__ V,
                                              h16* __restrict__ O) {
  __shared__ __align__(16) h16 Ksh[128 * 72];
  __shared__ __align__(16) h16 Vsh[64 * 136];
  __shared__ __align__(16) h16 Psh[4][16 * 136];

  const int qb0 = blockIdx.x * 64;
  const int bh = blockIdx.y;
  const int b = bh >> 4, h = bh & 15;
  const int tid = threadIdx.x;
  const int wave = tid >> 6, lane = tid & 63;
  const int lr = lane & 15, lg = lane >> 4;

  const h16* Qb = Q + (size_t)b * 2048 * 1024 + h * 64;
  const h16* Kb = K + (size_t)b * 2048 * 1024 + h * 64;
  const h16* Vb = V + (size_t)b * 2048 * 1024 + h * 64;

#pragma unroll
  for (int i = 0; i < 4; ++i) {
    const int c = tid * 4 + i;
    const int row = c >> 3, c8 = c & 7;
    const int t = qb0 - 32 + row;
    h8 kv, vv;
    if (t >= 0 && t < 2048) {
      kv = *(const h8*)&Kb[(size_t)t * 1024 + c8 * 8];
      vv = *(const h8*)&Vb[(size_t)t * 1024 + c8 * 8];
    } else {
#pragma unroll
      for (int j = 0; j < 8; ++j) { kv[j] = (h16)0.f; vv[j] = (h16)0.f; }
    }
    *(h8*)&Ksh[row * 72 + c8 * 8] = kv;
#pragma unroll
    for (int j = 0; j < 8; ++j) Vsh[(c8 * 8 + j) * 136 + row] = vv[j];
  }
  __syncthreads();

  const int qrow = qb0 + wave * 16 + lr;
  h8 qa[2];
#pragma unroll
  for (int kk = 0; kk < 2; ++kk)
    qa[kk] = *(const h8*)&Qb[(size_t)qrow * 1024 + kk * 32 + lg * 8];

  f32x4 sacc[8] = {};
#pragma unroll
  for (int n = 0; n < 8; ++n)
#pragma unroll
    for (int kk = 0; kk < 2; ++kk) {
      h8 kb = *(const h8*)&Ksh[(n * 16 + lr) * 72 + kk * 32 + lg * 8];
      sacc[n] = __builtin_amdgcn_mfma_f32_16x16x32_f16(qa[kk], kb, sacc[n], 0, 0, 0);
    }

  float p[8][4];
#pragma unroll
  for (int j = 0; j < 4; ++j) {
    const int wrow = wave * 16 + lg * 4 + j;
    float mx = -1e30f;
#pragma unroll
    for (int n = 0; n < 8; ++n) {
      const int d = n * 16 + lr - wrow;
      float s = (d < 0 || d > 64) ? -1e30f : sacc[n][j] * 0.125f;
      p[n][j] = s;
      mx = fmaxf(mx, s);
    }
#pragma unroll
    for (int off = 1; off < 16; off <<= 1) mx = fmaxf(mx, __shfl_xor(mx, off, 64));
    float sum = 0.f;
#pragma unroll
    for (int n = 0; n < 8; ++n) {
      const float e = __expf(p[n][j] - mx);
      p[n][j] = e;
      sum += e;
    }
#pragma unroll
    for (int off = 1; off < 16; off <<= 1) sum += __shfl_xor(sum, off, 64);
    const float inv = 1.f / sum;
#pragma unroll
    for (int n = 0; n < 8; ++n) p[n][j] *= inv;
  }

#pragma unroll
  for (int n = 0; n < 8; ++n)
#pragma unroll
    for (int j = 0; j < 4; ++j)
      Psh[wave][(lg * 4 + j) * 136 + n * 16 + lr] = (h16)p[n][j];
  __syncthreads();

  f32x4 oacc[4] = {};
#pragma unroll
  for (int kk = 0; kk < 4; ++kk) {
    h8 pa = *(const h8*)&Psh[wave][lr * 136 + kk * 32 + lg * 8];
#pragma unroll
    for (int n = 0; n < 4; ++n) {
      h8 vb = *(const h8*)&Vsh[(n * 16 + lr) * 136 + kk * 32 + lg * 8];
      oacc[n] = __builtin_amdgcn_mfma_f32_16x16x32_f16(pa, vb, oacc[n], 0, 0, 0);
    }
  }

#pragma unroll
  for (int n = 0; n < 4; ++n)
#pragma unroll
    for (int j = 0; j < 4; ++j) {
      const int s = qb0 + wave * 16 + lg * 4 + j;
      const int d = n * 16 + lr;
      O[((size_t)b * 2048 + s) * 1024 + h * 64 + d] = (h16)oacc[n][j];
    }
}

extern "C" void kernel_launch(void* const* d_in, const int* in_sizes, int n_in,
                              void* d_out, int out_size, void* d_ws, size_t ws_size,
                              hipStream_t stream) {
  const float* hs = (const float*)d_in[0];
  const float* qw = (const float*)d_in[1];
  const float* qb = (const float*)d_in[2];
  const float* kw = (const float*)d_in[3];
  const float* kb = (const float*)d_in[4];
  const float* vw = (const float*)d_in[5];
  const float* vb = (const float*)d_in[6];
  const float* ow = (const float*)d_in[7];
  const float* ob = (const float*)d_in[8];

  const int M = in_sizes[0] / 1024;  // B * S = 4096

  h16* hsH = (h16*)d_ws;
  h16* wqkv = hsH + (size_t)M * 1024;
  h16* woH = wqkv + (size_t)3072 * 1024;
  h16* qH = woH + (size_t)1024 * 1024;  // [B,S,E]
  h16* kH = qH + (size_t)M * 1024;
  h16* vH = kH + (size_t)M * 1024;
  h16* attnH = vH + (size_t)M * 1024;   // [B,S,E]

  const int tot = M * 1024 + 4 * 1048576;
  f2h_all<<<(tot / 8 + 255) / 256, 256, 0, stream>>>(hs, qw, kw, vw, ow, hsH,
                                                     M * 1024);

  // QKV: 128x64 tiles, grid 1536 -> 6 blocks/CU
  qkv10<<<1536, 256, 0, stream>>>(hsH, wqkv, qb, kb, vb, qH, kH, vH);

  swattn<<<dim3(32, M / 2048 * 16), 256, 0, stream>>>(qH, kH, vH, attnH);

  // O-proj: 64x64 tiles, grid 1024 -> 4 blocks/CU
  oproj10<<<1024, 256, 0, stream>>>(attnH, woH, ob, (float*)d_out);
}